// Round 7
// baseline (323.826 us; speedup 1.0000x reference)
//
#include <hip/hip_runtime.h>

// TextCNN: B=128, S=512, E=300, H=64, k_i = i/2+2 in [2,33].
// Virtual-im2col bf16 MFMA GEMM, fused gather, 4-chunk E-split LDS staging.
//   Grid: 128 b x 8 t-slices (64 rows each) = 1024 blocks = exactly 4/CU,
//   zero tile waste (8*64 = 512).
//   Block: 256 thr = 4 waves = (p: 2 M-tiles, 32 rows) x (jh: balanced j-half).
//   UNIFIED-REGISTER RULE (R6 post-mortem): occupancy cap = unified VGPR+AGPR.
//   R3/R6's acc[3][4]=48 AGPR + 84 arch = 132 -> floor(512/132) = 3 waves/SIMD
//   (the 30% occupancy both measured). acc[2][4]=32 AGPR + ~76 arch = ~108
//   < 128 -> 4 waves/SIMD. launch_bounds(256,3) kept (cap 170, never forces
//   a squeeze -- R4/R5 showed cap<demand cascades into catastrophic spill).
//   A-reads optimal: each unique (j,u,t) LDS frag read once per block (1320).
//   B-steps read by both p-waves (same order, adjacent -> L1 absorbs).
//   j-halves: jh0 = [0,9)x4g + [25,31)x1g = 42 units; jh1 = [9,17)x3g +
//   [17,25)x2g + [31,33)x1g = 42 units -> exact per-SIMD MFMA balance.
//   Epilogue: 2-phase jh reduce in LDS (store, add), tanh + masked max.
//   LDS: 96 rows (64+32 halo) x 208 B = 19.5 KB; epilogue reuse 18 KB.
// ws layout: [0, 860160) wsB bf16 | [860160, +262144) wsF f32 (128*64*8).

#define SS     512
#define EE     300
#define HH     64
#define KMAXW  33
#define LP     104          // LDS row pitch in elems (208 B); 52 dw == 20 mod 32
#define RP     68           // epilogue reduce pitch (floats)

typedef __attribute__((ext_vector_type(8))) short bf16x8;
typedef __attribute__((ext_vector_type(4))) float f32x4;

__device__ __forceinline__ unsigned short f2bf(float f) {
    unsigned u = __float_as_uint(f);
    unsigned r = ((u >> 16) & 1u) + 0x7FFFu;   // round-to-nearest-even
    return (unsigned short)((u + r) >> 16);
}

// ---- Kernel 1: repack Wconv (f32 [64][33][300]) -> wsB bf16, fragment order.
// Layout: [chunk c][group g][j*uc+u][512], uc = {3,3,3,1}, chunk base = c*129024.
// Group step-bases within chunk: CUMJ[g]*uc, CUMJ = {0,9,26,51} (Jg = 8g+9).
__global__ __launch_bounds__(256) void prep_weights(const float* __restrict__ Wconv,
                                                    unsigned short* __restrict__ wsB) {
    int idx = blockIdx.x * 256 + threadIdx.x;      // < 430080
    int r    = idx & 7;
    int lane = (idx >> 3) & 63;
    int gs   = idx >> 9;                           // < 840 steps
    int c, w2, uc;
    if (gs < 756) { c = gs / 252; w2 = gs - c * 252; uc = 3; }
    else          { c = 3;        w2 = gs - 756;     uc = 1; }
    int g, t;
    if (uc == 3) {
        if      (w2 < 27)  { g = 0; t = w2;       }
        else if (w2 < 78)  { g = 1; t = w2 - 27;  }
        else if (w2 < 153) { g = 2; t = w2 - 78;  }
        else               { g = 3; t = w2 - 153; }
    } else {
        if      (w2 < 9)   { g = 0; t = w2;       }
        else if (w2 < 26)  { g = 1; t = w2 - 9;   }
        else if (w2 < 51)  { g = 2; t = w2 - 26;  }
        else               { g = 3; t = w2 - 51;  }
    }
    int j = t / uc, u = t - j * uc;
    int i  = g * 16 + (lane & 15);
    int ki = i / 2 + 2;
    int kk = (lane >> 4) * 8 + r;
    int e  = c * 96 + u * 32 + kk;
    float v = 0.f;
    if (e < EE && j < ki) v = Wconv[(i * KMAXW + j) * EE + e];
    wsB[idx] = f2bf(v);
}

#define MFMA(A, Bf, C) __builtin_amdgcn_mfma_f32_16x16x32_bf16((A), (Bf), (C), 0, 0, 0)

// One j-segment of one chunk: groups g in [G0,4) active (G-pure j range).
// ar0 = At + (p*32+m)*LP + q*8; bp = wsB + c*129024 + lane*8.
// B loaded first (<= 4 frags live), then one a-frag streams through its MFMAs.
template<int G0, int UC>
__device__ __forceinline__ void seg(const unsigned short* __restrict__ ar0,
                                    int jlo, int jhi,
                                    const unsigned short* __restrict__ bp,
                                    f32x4 acc[2][4]) {
    constexpr int CUMJ[4] = {0, 9, 26, 51};
    #pragma unroll 1
    for (int j = jlo; j < jhi; ++j) {
        const unsigned short* ar = ar0 + j * LP;
        #pragma unroll
        for (int u = 0; u < UC; ++u) {
            bf16x8 bf[4];
            #pragma unroll
            for (int g = G0; g < 4; ++g)
                bf[g] = *(const bf16x8*)(bp + ((CUMJ[g] + j) * UC + u) * 512);
            #pragma unroll
            for (int t = 0; t < 2; ++t) {
                bf16x8 a = *(const bf16x8*)(ar + t * (16 * LP) + u * 32);
                #pragma unroll
                for (int g = G0; g < 4; ++g)
                    acc[t][g] = MFMA(a, bf[g], acc[t][g]);
            }
        }
    }
}

// ---- Kernel 2: fused gather + GEMM + cross-wave reduce + tanh + masked max.
__global__ __launch_bounds__(256, 3) void conv_fused(const int* __restrict__ x,
                                                     const float* __restrict__ emb,
                                                     const unsigned short* __restrict__ wsB,
                                                     const float* __restrict__ bconv,
                                                     float* __restrict__ wsF) {
    __shared__ __align__(16) unsigned short At[96 * LP];   // 19968 B

    int b     = blockIdx.x >> 3;
    int slice = blockIdx.x & 7;
    int t0    = slice * 64;

    int lane = threadIdx.x & 63;
    int w    = threadIdx.x >> 6;       // 0..3
    int p    = w >> 1;                 // M-half: 2 tiles of 16 rows
    int jh   = w & 1;                  // j-half (SIMD-balanced, 42 units each)
    int m = lane & 15, q = lane >> 4;

    f32x4 acc[2][4] = {};

    const unsigned short* ar0 = At + (p * 32 + m) * LP + q * 8;

    #pragma unroll 1
    for (int c = 0; c < 4; ++c) {
        if (c) __syncthreads();        // all reads of previous chunk complete

        // Stage 96 rows (64 + 32 halo) of chunk c, f32 -> bf16, zero-padded.
        if (c < 3) {                   // 96 elems/row = 12 bf16x8
            #pragma unroll
            for (int it = 0; it < 5; ++it) {
                int idx = threadIdx.x + it * 256;          // < 1280
                if (idx < 1152) {
                    int rr = idx / 12, cc = idx - rr * 12;
                    int srow = t0 + rr;
                    bf16x8 v = {0, 0, 0, 0, 0, 0, 0, 0};
                    if (srow < SS) {
                        int tok = x[b * SS + srow];
                        const float* ep = emb + (long)tok * EE + c * 96 + cc * 8;
                        float4 f0 = ((const float4*)ep)[0];
                        float4 f1 = ((const float4*)ep)[1];
                        v[0] = f2bf(f0.x); v[1] = f2bf(f0.y); v[2] = f2bf(f0.z); v[3] = f2bf(f0.w);
                        v[4] = f2bf(f1.x); v[5] = f2bf(f1.y); v[6] = f2bf(f1.z); v[7] = f2bf(f1.w);
                    }
                    *(bf16x8*)&At[rr * LP + cc * 8] = v;
                }
            }
        } else {                       // elems 288..299 valid, pad to 32
            #pragma unroll
            for (int it = 0; it < 2; ++it) {
                int idx = threadIdx.x + it * 256;          // < 512
                if (idx < 384) {
                    int rr = idx >> 2, cc = idx & 3;
                    int srow = t0 + rr;
                    bf16x8 v = {0, 0, 0, 0, 0, 0, 0, 0};
                    if (srow < SS && cc < 2) {
                        int tok = x[b * SS + srow];
                        const float* ep = emb + (long)tok * EE + 288 + cc * 8;
                        float4 f0 = ((const float4*)ep)[0];
                        v[0] = f2bf(f0.x); v[1] = f2bf(f0.y); v[2] = f2bf(f0.z); v[3] = f2bf(f0.w);
                        if (cc == 0) {                     // 288..295 all valid
                            float4 f1 = ((const float4*)ep)[1];
                            v[4] = f2bf(f1.x); v[5] = f2bf(f1.y); v[6] = f2bf(f1.z); v[7] = f2bf(f1.w);
                        }                                  // cc==1: 296..299 only
                    }
                    *(bf16x8*)&At[rr * LP + cc * 8] = v;
                }
            }
        }
        __syncthreads();

        const unsigned short* bp = wsB + c * 129024 + lane * 8;
        // j-regions by active-group count: [0,9):4g, [9,17):3g, [17,25):2g, [25,33):1g.
        // jh0: [0,9) + [25,31) = 36+6 = 42 units; jh1: [9,25) + [31,33) = 40+2 = 42.
        if (c < 3) {
            if (jh == 0) { seg<0,3>(ar0, 0, 9,  bp, acc); seg<3,3>(ar0, 25, 31, bp, acc); }
            else         { seg<1,3>(ar0, 9, 17, bp, acc); seg<2,3>(ar0, 17, 25, bp, acc);
                           seg<3,3>(ar0, 31, 33, bp, acc); }
        } else {
            if (jh == 0) { seg<0,1>(ar0, 0, 9,  bp, acc); seg<3,1>(ar0, 25, 31, bp, acc); }
            else         { seg<1,1>(ar0, 9, 17, bp, acc); seg<2,1>(ar0, 17, 25, bp, acc);
                           seg<3,1>(ar0, 31, 33, bp, acc); }
        }
    }

    // ---- Epilogue: 2-phase jh reduce in LDS (store, add), tanh + masked max.
    __syncthreads();                                  // done reading At
    float* red  = (float*)At;                         // [64][RP] = 17408 B
    float* red2 = red + 64 * RP;                      // [4][64]  = 1024 B (18432 <= 19968)

    // C/D map: col = m (filter in group), row = p*32 + t*16 + q*4 + r.
    if (jh == 0) {
        #pragma unroll
        for (int t = 0; t < 2; ++t)
            #pragma unroll
            for (int g = 0; g < 4; ++g)
                #pragma unroll
                for (int r = 0; r < 4; ++r)
                    red[(p * 32 + t * 16 + q * 4 + r) * RP + g * 16 + m] = acc[t][g][r];
    }
    __syncthreads();
    if (jh == 1) {
        #pragma unroll
        for (int t = 0; t < 2; ++t)
            #pragma unroll
            for (int g = 0; g < 4; ++g)
                #pragma unroll
                for (int r = 0; r < 4; ++r)
                    red[(p * 32 + t * 16 + q * 4 + r) * RP + g * 16 + m] += acc[t][g][r];
    }
    __syncthreads();

    int f  = threadIdx.x & 63;                        // filter
    int rg = threadIdx.x >> 6;                        // row group (16 rows each)
    int ki = (f >> 1) + 2;
    int tmax = SS - ki;
    float bc = bconv[f];
    float mx = -3.0e38f;
    #pragma unroll 1
    for (int rr = 0; rr < 16; ++rr) {
        int row = rg * 16 + rr;
        int tb  = t0 + row;
        float v = tanhf(red[row * RP + f] + bc);
        if (tb <= tmax) mx = fmaxf(mx, v);
    }
    red2[rg * 64 + f] = mx;
    __syncthreads();
    if (threadIdx.x < 64) {
        float v = fmaxf(fmaxf(red2[f], red2[64 + f]),
                        fmaxf(red2[128 + f], red2[192 + f]));
        wsF[(b * HH + f) * 8 + slice] = v;
    }
}

// ---- Kernel 3: max over 8 partials, linear, sigmoid. 128 blocks x 64 thr.
__global__ __launch_bounds__(64) void final_linear(const float* __restrict__ wsF,
                                                   const float* __restrict__ Wlin,
                                                   const float* __restrict__ blin,
                                                   float* __restrict__ out) {
    int b = blockIdx.x;
    int i = threadIdx.x;
    const float* pp = wsF + (b * HH + i) * 8;
    float mx = pp[0];
    #pragma unroll
    for (int j = 1; j < 8; ++j) mx = fmaxf(mx, pp[j]);
    float v = mx * Wlin[i];
    #pragma unroll
    for (int off = 1; off < 64; off <<= 1) v += __shfl_xor(v, off);
    if (i == 0) out[b] = 1.0f / (1.0f + expf(-(v + blin[0])));
}

extern "C" void kernel_launch(void* const* d_in, const int* in_sizes, int n_in,
                              void* d_out, int out_size, void* d_ws, size_t ws_size,
                              hipStream_t stream) {
    const int*   x     = (const int*)d_in[0];
    const float* emb   = (const float*)d_in[1];
    const float* Wconv = (const float*)d_in[2];
    const float* bconv = (const float*)d_in[3];
    const float* Wlin  = (const float*)d_in[4];
    const float* blin  = (const float*)d_in[5];
    float* out = (float*)d_out;

    unsigned short* wsB = (unsigned short*)d_ws;
    float*          wsF = (float*)((char*)d_ws + 860160);   // wsB = 430080*2 B

    prep_weights<<<1680, 256, 0, stream>>>(Wconv, wsB);
    conv_fused<<<1024, 256, 0, stream>>>(x, emb, wsB, bconv, wsF);
    final_linear<<<128, 64, 0, stream>>>(wsF, Wlin, blin, out);
}

// Round 8
// 166.692 us; speedup vs baseline: 1.9427x; 1.9427x over previous
//
#include <hip/hip_runtime.h>

// TextCNN: B=128, S=512, E=300, H=64, k_i = i/2+2 in [2,33].
// Virtual-im2col bf16 MFMA GEMM, fused gather, E-split LDS staging.
//   == R3 structure (best verified: conv_fused 106us) + register B-prefetch ==
//   Grid: 128 b x 6 t-slices (96 rows each) = 768 blocks = 3/CU resident.
//   Block: 4 waves = 2-way M-split (p) x 2-way j(K)-split (jh), acc[3][4].
//   R7 post-mortem: occupancy cannot be raised reliably (unified-reg model
//   falsified: 104 regs still measured 23.7%); kernel is latency-bound INSIDE
//   compute phases at 3 waves/SIMD. Fix at fixed occupancy: software-pipeline
//   the global B-frag loads one (j,u)-step ahead (bc/bn rotation) so the
//   ~200-300cy L2 latency rides under the 12-MFMA (~233cy) step issue.
//   +16 live VGPRs -> unified ~148 < 170 cap of (256,3): no spill expected
//   (spill signature: VGPR arch >130 or WRITE_SIZE >> 5MB).
//   Tail prefetch reads one step past seg end: max byte 861KB < 1MB wsF
//   offset -> in-workspace, value discarded.
//   Epilogue: 2-phase jh reduce in LDS (store, add), tanh + masked max.
//   LDS: 128 rows x 168-elem half-rows = 42 KB -> 3 blocks/CU.
// ws layout: [0, 860KB) wsB bf16 | [1MB, +192KB) wsF f32 (128*64*6).

#define SS     512
#define EE     300
#define HH     64
#define KMAXW  33
#define LP     168          // LDS half-row pitch in elems (336 B)
#define HALFSZ 215040       // wsB elems per E-half (420 steps * 512)
#define RP     68           // epilogue reduce pitch (floats)

typedef __attribute__((ext_vector_type(8))) short bf16x8;
typedef __attribute__((ext_vector_type(4))) float f32x4;

__device__ __forceinline__ unsigned short f2bf(float f) {
    unsigned u = __float_as_uint(f);
    unsigned r = ((u >> 16) & 1u) + 0x7FFFu;   // round-to-nearest-even
    return (unsigned short)((u + r) >> 16);
}

// ---- Kernel 1: repack Wconv (f32 [64][33][300]) -> wsB bf16, fragment order.
// step id within (half, group): j*5+u, u indexes 32-elem sub-blocks of the 160-elem half.
__global__ __launch_bounds__(256) void prep_weights(const float* __restrict__ Wconv,
                                                    unsigned short* __restrict__ wsB) {
    int idx = blockIdx.x * 256 + threadIdx.x;      // < 430080
    int r    = idx & 7;
    int lane = (idx >> 3) & 63;
    int gs   = idx >> 9;                           // < 840
    int h    = gs / 420;
    int ww   = gs - h * 420;
    int g, t;
    if      (ww < 45)  { g = 0; t = ww;       }
    else if (ww < 130) { g = 1; t = ww - 45;  }
    else if (ww < 255) { g = 2; t = ww - 130; }
    else               { g = 3; t = ww - 255; }
    int j = t / 5, u = t - j * 5;
    int i  = g * 16 + (lane & 15);
    int ki = i / 2 + 2;
    int kk = (lane >> 4) * 8 + r;
    int e  = h * 160 + u * 32 + kk;
    float v = 0.f;
    if (e < EE && j < ki) v = Wconv[(i * KMAXW + j) * EE + e];
    wsB[idx] = f2bf(v);
}

#define MFMA(A, Bf, C) __builtin_amdgcn_mfma_f32_16x16x32_bf16((A), (Bf), (C), 0, 0, 0)

// One j-segment: groups g in [G0,4) are active (segment must lie in a G-pure j range).
// ar0 = At + (p*48+m)*LP + q*8 (lane's A base); bp = wsB half base + lane*8.
// Register B-prefetch: bc holds step s's frags, bn issues step s+1's loads
// before the MFMAs -> B L2 latency hides under the 12-MFMA step issue.
template<int G0>
__device__ __forceinline__ void seg(const unsigned short* __restrict__ ar0,
                                    int jlo, int jhi,
                                    const unsigned short* __restrict__ bp,
                                    f32x4 acc[3][4]) {
    constexpr int GBASE[4] = {0, 45, 130, 255};
    bf16x8 bc[4];
    #pragma unroll
    for (int g = G0; g < 4; ++g)
        bc[g] = *(const bf16x8*)(bp + (GBASE[g] + jlo * 5) * 512);
    #pragma unroll 1
    for (int j = jlo; j < jhi; ++j) {
        const unsigned short* ar = ar0 + j * LP;
        const unsigned short* br = bp + j * 5 * 512;
        #pragma unroll
        for (int u = 0; u < 5; ++u) {
            bf16x8 bn[4];
            #pragma unroll
            for (int g = G0; g < 4; ++g)     // next step (u+1; at u=4 -> (j+1,0))
                bn[g] = *(const bf16x8*)(br + (GBASE[g] + u + 1) * 512);
            #pragma unroll
            for (int t = 0; t < 3; ++t) {
                bf16x8 a = *(const bf16x8*)(ar + t * (16 * LP) + u * 32);
                #pragma unroll
                for (int g = G0; g < 4; ++g)
                    acc[t][g] = MFMA(a, bc[g], acc[t][g]);
            }
            #pragma unroll
            for (int g = G0; g < 4; ++g) bc[g] = bn[g];
        }
    }
}

// ---- Kernel 2: fused gather + GEMM + cross-wave reduce + tanh + masked max.
__global__ __launch_bounds__(256, 3) void conv_fused(const int* __restrict__ x,
                                                     const float* __restrict__ emb,
                                                     const unsigned short* __restrict__ wsB,
                                                     const float* __restrict__ bconv,
                                                     float* __restrict__ wsF) {
    __shared__ __align__(16) unsigned short At[128 * LP];   // 42 KB

    int b     = blockIdx.x / 6;
    int slice = blockIdx.x - b * 6;
    int t0    = slice * 96;

    int lane = threadIdx.x & 63;
    int w    = threadIdx.x >> 6;
    int p    = w >> 1;                 // M-half: 3 tiles of 16 rows
    int jh   = w & 1;                  // j-range half
    int m = lane & 15, q = lane >> 4;

    f32x4 acc[3][4] = {};

    const unsigned short* ar0 = At + (p * 48 + m) * LP + q * 8;

    for (int eh = 0; eh < 2; ++eh) {
        if (eh) __syncthreads();       // all reads of previous half complete

        // Stage 128 half-rows (96 + 32 halo), f32 -> bf16, zero-padded.
        #pragma unroll
        for (int it = 0; it < 10; ++it) {
            int idx = threadIdx.x + it * 256;      // < 2560
            int rr = idx / 20, c = idx - rr * 20;
            int srow = t0 + rr;
            bf16x8 v = {0, 0, 0, 0, 0, 0, 0, 0};
            if (srow < SS) {
                int tok = x[b * SS + srow];
                const float* ep = emb + (long)tok * EE + eh * 160 + c * 8;
                if (eh == 0 || c < 17) {
                    float4 f0 = ((const float4*)ep)[0];
                    float4 f1 = ((const float4*)ep)[1];
                    v[0] = f2bf(f0.x); v[1] = f2bf(f0.y); v[2] = f2bf(f0.z); v[3] = f2bf(f0.w);
                    v[4] = f2bf(f1.x); v[5] = f2bf(f1.y); v[6] = f2bf(f1.z); v[7] = f2bf(f1.w);
                } else if (c == 17) {  // elems 296..299 valid
                    float4 f0 = ((const float4*)ep)[0];
                    v[0] = f2bf(f0.x); v[1] = f2bf(f0.y); v[2] = f2bf(f0.z); v[3] = f2bf(f0.w);
                }
            }
            *(bf16x8*)&At[rr * LP + c * 8] = v;
        }
        __syncthreads();

        const unsigned short* bp = wsB + eh * HALFSZ + lane * 8;
        // j-regions by active-group count: [0,9):4g, [9,17):3g, [17,25):2g, [25,33):1g.
        // jh0: [0,9)+[25,31) = 36+6 = 42 units; jh1: [9,25)+[31,33) = 40+2 = 42.
        // (1 unit = 5u x 3t = 15 MFMA) -> 630 MFMA/wave/half, exact SIMD balance.
        if (jh == 0) {
            seg<0>(ar0, 0, 9,  bp, acc);
            seg<3>(ar0, 25, 31, bp, acc);
        } else {
            seg<1>(ar0, 9, 17, bp, acc);
            seg<2>(ar0, 17, 25, bp, acc);
            seg<3>(ar0, 31, 33, bp, acc);
        }
    }

    // ---- Epilogue: 2-phase jh-partial reduce in LDS, then tanh + masked max.
    __syncthreads();                                  // done reading At
    float* red  = (float*)At;                         // [96][RP] = 26112 B
    float* red2 = red + 96 * RP;                      // [4][64]  = 1024 B

    // C/D map: col = m (filter in group), row = p*48 + t*16 + q*4 + r.
    if (jh == 0) {
        #pragma unroll
        for (int t = 0; t < 3; ++t)
            #pragma unroll
            for (int g = 0; g < 4; ++g)
                #pragma unroll
                for (int r = 0; r < 4; ++r)
                    red[(p * 48 + t * 16 + q * 4 + r) * RP + g * 16 + m] = acc[t][g][r];
    }
    __syncthreads();
    if (jh == 1) {
        #pragma unroll
        for (int t = 0; t < 3; ++t)
            #pragma unroll
            for (int g = 0; g < 4; ++g)
                #pragma unroll
                for (int r = 0; r < 4; ++r)
                    red[(p * 48 + t * 16 + q * 4 + r) * RP + g * 16 + m] += acc[t][g][r];
    }
    __syncthreads();

    int f  = threadIdx.x & 63;                        // filter
    int rg = threadIdx.x >> 6;                        // row group (24 rows each)
    int ki = (f >> 1) + 2;
    int tmax = SS - ki;
    float bc = bconv[f];
    float mx = -3.0e38f;
    #pragma unroll 1
    for (int rr = 0; rr < 24; ++rr) {
        int row = rg * 24 + rr;
        int tb  = t0 + row;
        float v = tanhf(red[row * RP + f] + bc);
        if (tb <= tmax) mx = fmaxf(mx, v);
    }
    red2[rg * 64 + f] = mx;
    __syncthreads();
    if (threadIdx.x < 64) {
        float v = fmaxf(fmaxf(red2[f], red2[64 + f]),
                        fmaxf(red2[128 + f], red2[192 + f]));
        wsF[(b * HH + f) * 6 + slice] = v;
    }
}

// ---- Kernel 3: max over 6 partials, linear, sigmoid. 128 blocks x 64 thr.
__global__ __launch_bounds__(64) void final_linear(const float* __restrict__ wsF,
                                                   const float* __restrict__ Wlin,
                                                   const float* __restrict__ blin,
                                                   float* __restrict__ out) {
    int b = blockIdx.x;
    int i = threadIdx.x;
    const float* pp = wsF + (b * HH + i) * 6;
    float mx = pp[0];
    #pragma unroll
    for (int j = 1; j < 6; ++j) mx = fmaxf(mx, pp[j]);
    float v = mx * Wlin[i];
    #pragma unroll
    for (int off = 1; off < 64; off <<= 1) v += __shfl_xor(v, off);
    if (i == 0) out[b] = 1.0f / (1.0f + expf(-(v + blin[0])));
}

extern "C" void kernel_launch(void* const* d_in, const int* in_sizes, int n_in,
                              void* d_out, int out_size, void* d_ws, size_t ws_size,
                              hipStream_t stream) {
    const int*   x     = (const int*)d_in[0];
    const float* emb   = (const float*)d_in[1];
    const float* Wconv = (const float*)d_in[2];
    const float* bconv = (const float*)d_in[3];
    const float* Wlin  = (const float*)d_in[4];
    const float* blin  = (const float*)d_in[5];
    float* out = (float*)d_out;

    unsigned short* wsB = (unsigned short*)d_ws;
    float*          wsF = (float*)((char*)d_ws + (1u << 20));

    prep_weights<<<1680, 256, 0, stream>>>(Wconv, wsB);
    conv_fused<<<768, 256, 0, stream>>>(x, emb, wsB, bconv, wsF);
    final_linear<<<128, 64, 0, stream>>>(wsF, Wlin, blin, out);
}